// Round 1
// baseline (290.322 us; speedup 1.0000x reference)
//
#include <hip/hip_runtime.h>
#include <hip/hip_bf16.h>
#include <math.h>

#define NB 128
#define NS 256
#define NH 768
#define NL 24

// ---------------- Kernel A: emissions = sigmoid(tf[b,t+1,:] @ W + b) for t < n_b ----
// grid 512 = 128 batches x 4 tiles of 64 tokens; block 384 = 24 labels x 16 token-quads
__global__ __launch_bounds__(384) void ner_emis(
    const float* __restrict__ tf, const int* __restrict__ tlm,
    const float* __restrict__ W, const float* __restrict__ bias,
    float* __restrict__ E)
{
    const int b    = blockIdx.x >> 2;
    const int tile = (blockIdx.x & 3) << 6;
    const int tid  = threadIdx.x;
    // true_label_mask is a prefix mask: if tile start invalid, whole tile invalid
    if (tlm[b*NS + tile] == 0) return;

    __shared__ float Wl[NH*NL];   // 72 KB
    {
        const float4* W4 = (const float4*)W;
        float4* Wl4 = (float4*)Wl;
        #pragma unroll
        for (int i = 0; i < 12; ++i) Wl4[tid + i*384] = W4[tid + i*384];
    }
    __syncthreads();

    const int l  = tid % 24;
    const int tq = tid / 24;              // 0..15
    const int t0 = tile + (tq << 2);
    const int* tm = tlm + b*NS;

    const bool v0 = tm[t0+0] != 0, v1 = tm[t0+1] != 0, v2 = tm[t0+2] != 0, v3 = tm[t0+3] != 0;
    if (!v0) return;                       // prefix mask: all 4 tokens invalid

    const float* base = tf + (size_t)(b*NS)*NH;
    const float* r0 = base + (size_t)(t0+1)*NH;            // token t uses feature row t+1
    const float* r1 = base + (size_t)(v1 ? t0+2 : 0)*NH;
    const float* r2 = base + (size_t)(v2 ? t0+3 : 0)*NH;
    const float* r3 = base + (size_t)(v3 ? t0+4 : 0)*NH;

    float acc0=0.f, acc1=0.f, acc2=0.f, acc3=0.f;
    for (int k = 0; k < NH; k += 4) {
        float4 a0 = *(const float4*)(r0 + k);
        float4 a1 = *(const float4*)(r1 + k);
        float4 a2 = *(const float4*)(r2 + k);
        float4 a3 = *(const float4*)(r3 + k);
        float w0 = Wl[(k+0)*NL + l];
        float w1 = Wl[(k+1)*NL + l];
        float w2 = Wl[(k+2)*NL + l];
        float w3 = Wl[(k+3)*NL + l];
        acc0 += a0.x*w0 + a0.y*w1 + a0.z*w2 + a0.w*w3;
        acc1 += a1.x*w0 + a1.y*w1 + a1.z*w2 + a1.w*w3;
        acc2 += a2.x*w0 + a2.y*w1 + a2.z*w2 + a2.w*w3;
        acc3 += a3.x*w0 + a3.y*w1 + a3.z*w2 + a3.w*w3;
    }
    const float bl = bias[l];
    float* Eb = E + (size_t)(b*NS)*NL;
    if (v0) { float x = acc0 + bl; Eb[(t0+0)*NL + l] = 1.0f/(1.0f + expf(-x)); }
    if (v1) { float x = acc1 + bl; Eb[(t0+1)*NL + l] = 1.0f/(1.0f + expf(-x)); }
    if (v2) { float x = acc2 + bl; Eb[(t0+2)*NL + l] = 1.0f/(1.0f + expf(-x)); }
    if (v3) { float x = acc3 + bl; Eb[(t0+3)*NL + l] = 1.0f/(1.0f + expf(-x)); }
}

// ---------------- Kernel B: masked Viterbi decode, one block (256 thr) per batch ----
__global__ __launch_bounds__(256) void ner_viterbi(
    const float* __restrict__ E, const int* __restrict__ tlm,
    const float* __restrict__ trans, const float* __restrict__ st,
    const float* __restrict__ en, int* __restrict__ out)
{
    const int tid = threadIdx.x;
    const int b   = blockIdx.x;
    const int bS  = b*NS;

    __shared__ float scl[NS*NL];            // per-step score vectors (24.5 KB)
    __shared__ float Tt[NL*NL];             // Tt[c*24+p] = T[p][c] (transposed, for backtrack)
    __shared__ float fin[NL];
    __shared__ unsigned char tr_s[NL][NS];  // trace[hypothesis][t]
    __shared__ int chosen[12];
    __shared__ int nsh, ltag;

    for (int i = tid; i < NL*NL; i += 256) {
        int c = i / NL, p = i % NL;
        Tt[i] = trans[p*NL + c];
    }
    if (tid < 64) {   // n = sum(true_label_mask[b]) = lengths[b]-2  (contiguous prefix)
        int a = tlm[bS+tid] + tlm[bS+tid+64] + tlm[bS+tid+128] + tlm[bS+tid+192];
        #pragma unroll
        for (int off = 32; off > 0; off >>= 1) a += __shfl_down(a, off, 64);
        if (tid == 0) nsh = a;
    }
    __syncthreads();
    const int n = nsh;   // n >= 1 always (lengths >= 3)

    // ---- forward pass: wave 0 only, lane = curr tag (replicated x2.67) ----
    if (tid < 64) {
        const int c = tid % 24;
        float Tc[24];                        // column c of transitions, in VGPRs
        #pragma unroll
        for (int p = 0; p < 24; ++p) Tc[p] = trans[p*NL + c];

        auto rl = [](float v, int p) {       // broadcast lane p -> uniform (SGPR)
            return __int_as_float(__builtin_amdgcn_readlane(__float_as_int(v), p));
        };

        float sv = st[c] + E[(size_t)bS*NL + c];   // score0 = start + em[0]
        scl[c] = sv;
        float scr[24];
        #pragma unroll
        for (int p = 0; p < 24; ++p) scr[p] = rl(sv, p);

        auto step = [&](int t, float em) {
            float cand[24];
            #pragma unroll
            for (int p = 0; p < 24; ++p) cand[p] = scr[p] + Tc[p];
            float m0 = fmaxf(fmaxf(cand[0],  cand[1]),  cand[2]);
            float m1 = fmaxf(fmaxf(cand[3],  cand[4]),  cand[5]);
            float m2 = fmaxf(fmaxf(cand[6],  cand[7]),  cand[8]);
            float m3 = fmaxf(fmaxf(cand[9],  cand[10]), cand[11]);
            float m4 = fmaxf(fmaxf(cand[12], cand[13]), cand[14]);
            float m5 = fmaxf(fmaxf(cand[15], cand[16]), cand[17]);
            float m6 = fmaxf(fmaxf(cand[18], cand[19]), cand[20]);
            float m7 = fmaxf(fmaxf(cand[21], cand[22]), cand[23]);
            float q0 = fmaxf(fmaxf(m0, m1), m2);
            float q1 = fmaxf(fmaxf(m3, m4), m5);
            float q2 = fmaxf(m6, m7);
            float best = fmaxf(fmaxf(q0, q1), q2);
            sv = best + em;
            scl[t*NL + c] = sv;              // off critical path (deferred argmax)
            #pragma unroll
            for (int p = 0; p < 24; ++p) scr[p] = rl(sv, p);
        };

        // emission prefetch pipeline, depth 8
        float emv[8];
        #pragma unroll
        for (int j = 0; j < 8; ++j) {
            int tp = 1 + j; if (tp > n-1) tp = n-1;
            emv[j] = E[(size_t)(bS + tp)*NL + c];
        }
        int t = 1;
        for (; t + 8 <= n; t += 8) {
            #pragma unroll
            for (int j = 0; j < 8; ++j) {
                step(t + j, emv[j]);
                int tp = t + j + 8; if (tp > n-1) tp = n-1;
                emv[j] = E[(size_t)(bS + tp)*NL + c];
            }
        }
        for (; t < n; ++t) {
            float em = E[(size_t)(bS + t)*NL + c];
            step(t, em);
        }
        fin[c] = sv + en[c];
    }
    __syncthreads();

    if (tid == 0) {   // last_tag = argmax(final), first-max tie rule like jnp.argmax
        float bv = fin[0]; int bt = 0;
        #pragma unroll
        for (int cc = 1; cc < 24; ++cc) { if (fin[cc] > bv) { bv = fin[cc]; bt = cc; } }
        ltag = bt;
    }
    __syncthreads();

    // ---- backtrack: 10 windows x 24 hypotheses, recompute backpointers on the fly ----
    const int K = (n > 1) ? (n - 1 + 9) / 10 : 1;
    if (n > 1 && tid < 240) {
        const int w = tid / 24 + 1, h = tid % 24;
        int tlo = (w-1)*K; if (tlo > n-1) tlo = n-1;
        int thi = w*K;     if (thi > n-1) thi = n-1;
        int cur = h;                         // hypothesis: tag at time thi
        for (int t = thi; t > tlo; --t) {
            const float4* sp = (const float4*)(scl + (t-1)*NL);
            const float4* up = (const float4*)(Tt  + cur*NL);
            float cand[24];
            #pragma unroll
            for (int i = 0; i < 6; ++i) {
                float4 s = sp[i], u = up[i];
                cand[4*i+0] = s.x + u.x;     // bitwise-identical to forward cand
                cand[4*i+1] = s.y + u.y;
                cand[4*i+2] = s.z + u.z;
                cand[4*i+3] = s.w + u.w;
            }
            float best = cand[0]; int arg = 0;
            #pragma unroll
            for (int p = 1; p < 24; ++p) { if (cand[p] > best) { best = cand[p]; arg = p; } }
            tr_s[h][t-1] = (unsigned char)arg;
            cur = arg;
        }
    }
    __syncthreads();

    if (tid == 0) {   // stitch windows: chosen[w] = actual tag at window-top boundary
        int cur = ltag;
        for (int w = 10; w >= 1; --w) {
            chosen[w] = cur;
            int tlo = (w-1)*K; if (tlo > n-1) tlo = n-1;
            int thi = w*K;     if (thi > n-1) thi = n-1;
            if (thi > tlo) cur = tr_s[cur][tlo];
        }
    }
    __syncthreads();

    {   // emit path: t >= n-1 -> last_tag (identity backpointers on padding)
        const int t = tid;                   // 256 threads == NS
        int tag;
        if (t >= n-1) tag = ltag;
        else { int w = t / K + 1; tag = tr_s[chosen[w]][t]; }
        out[bS + t] = tag;
    }
}

extern "C" void kernel_launch(void* const* d_in, const int* in_sizes, int n_in,
                              void* d_out, int out_size, void* d_ws, size_t ws_size,
                              hipStream_t stream) {
    const float* tf    = (const float*)d_in[0];
    const int*   tlm   = (const int*)  d_in[2];   // true_label_mask
    const float* W     = (const float*)d_in[3];
    const float* bias  = (const float*)d_in[4];
    const float* trans = (const float*)d_in[5];
    const float* st    = (const float*)d_in[6];
    const float* en    = (const float*)d_in[7];
    float* E = (float*)d_ws;                      // [128,256,24] fp32 = 3.1 MB

    ner_emis<<<dim3(NB*4), dim3(384), 0, stream>>>(tf, tlm, W, bias, E);
    ner_viterbi<<<dim3(NB), dim3(256), 0, stream>>>(E, tlm, trans, st, en, (int*)d_out);
}

// Round 2
// 239.315 us; speedup vs baseline: 1.2131x; 1.2131x over previous
//
#include <hip/hip_runtime.h>
#include <hip/hip_bf16.h>
#include <math.h>

#define NB 128
#define NS 256
#define NH 768
#define NL 24

// ---------------- Kernel A: emissions = sigmoid(tf[b,t+1,:] @ W + b) for t < n_b ----
// grid 512 = 128 batches x 4 tiles of 64 tokens; block 256 thr = 4 waves.
// lane = token (64/tile); each lane keeps 24 accumulators; wave w covers k-quarter.
// W is read via wave-uniform pointers -> scalar (s_load) path, SGPR operand FMAs.
__global__ __launch_bounds__(256) void ner_emis(
    const float* __restrict__ tf, const int* __restrict__ tlm,
    const float* __restrict__ W, const float* __restrict__ bias,
    float* __restrict__ E)
{
    const int b    = blockIdx.x >> 2;
    const int tile = (blockIdx.x & 3) << 6;         // token base of this tile
    const int tid  = threadIdx.x;
    if (tlm[b*NS + tile] == 0) return;              // prefix mask: whole tile invalid

    __shared__ float As[64*129];                    // 64 tokens x 128 k, pad stride 129 (33 KB)
    __shared__ float Ps[4*64*NL];                   // per-wave partials (24.5 KB)

    const int lane = tid & 63;                      // token within tile
    const int w    = __builtin_amdgcn_readfirstlane(tid >> 6);  // wave id, force SGPR

    float acc[NL];
    #pragma unroll
    for (int l = 0; l < NL; ++l) acc[l] = 0.f;

    const float* tfb = tf + (size_t)(b*NS)*NH;

    for (int kc0 = 0; kc0 < NH; kc0 += 128) {
        // ---- stage A tile [64 tokens][128 k], coalesced float4, transpose-free ----
        #pragma unroll
        for (int i = 0; i < 8; ++i) {
            int idx  = tid + (i << 8);              // 0..2047 float4 slots
            int row  = idx >> 5;                    // token row 0..63
            int c4   = idx & 31;                    // float4 col 0..31
            int trow = tile + row + 1;              // feature row = token+1
            if (trow > 255) trow = 255;             // clamp (only invalid rows hit this)
            float4 v = *(const float4*)(tfb + (size_t)trow*NH + kc0 + (c4 << 2));
            float* dst = As + row*129 + (c4 << 2);
            dst[0] = v.x; dst[1] = v.y; dst[2] = v.z; dst[3] = v.w;
        }
        __syncthreads();

        // ---- compute: wave w handles k in [kc0 + 32w, kc0 + 32w + 32) ----
        const int kbase = kc0 + (w << 5);
        #pragma unroll
        for (int k = 0; k < 32; ++k) {
            float a = As[lane*129 + (w << 5) + k];  // bank = (lane+k)%32: conflict-free
            const float* wr = W + (size_t)(kbase + k)*NL;   // wave-uniform -> s_load
            #pragma unroll
            for (int l = 0; l < NL; ++l) acc[l] = fmaf(a, wr[l], acc[l]);
        }
        __syncthreads();
    }

    // ---- cross-wave reduction (fixed order = deterministic) ----
    {
        float* p = Ps + (w*64 + lane)*NL;
        #pragma unroll
        for (int l = 0; l < NL; ++l) p[l] = acc[l];
    }
    __syncthreads();

    const int* tm = tlm + b*NS + tile;
    float* Eb = E + (size_t)(b*NS + tile)*NL;
    #pragma unroll
    for (int j = 0; j < 6; ++j) {
        int idx = tid + (j << 8);                   // 0..1535 outputs (64 tok x 24 lab)
        int tok = idx / NL, l = idx % NL;
        if (tm[tok]) {
            float s = Ps[(0*64 + tok)*NL + l] + Ps[(1*64 + tok)*NL + l]
                    + Ps[(2*64 + tok)*NL + l] + Ps[(3*64 + tok)*NL + l];
            float x = s + bias[l];
            Eb[tok*NL + l] = 1.0f/(1.0f + expf(-x));
        }
    }
}

// ---------------- Kernel B: masked Viterbi decode, one block (256 thr) per batch ----
__global__ __launch_bounds__(256) void ner_viterbi(
    const float* __restrict__ E, const int* __restrict__ tlm,
    const float* __restrict__ trans, const float* __restrict__ st,
    const float* __restrict__ en, int* __restrict__ out)
{
    const int tid = threadIdx.x;
    const int b   = blockIdx.x;
    const int bS  = b*NS;

    __shared__ float Esh[NS*NL];            // preloaded emissions (24.5 KB)
    __shared__ float scl[NS*NL];            // per-step score vectors (24.5 KB)
    __shared__ float Tt[NL*NL];             // Tt[c*24+p] = T[p][c]
    __shared__ float fin[NL];
    __shared__ unsigned char tr_s[NL][NS];  // trace[hypothesis][t]
    __shared__ int chosen[12];
    __shared__ int nsh, ltag;

    // preload all emissions for this batch (rows >= n unused; poison harmless)
    {
        const float4* src = (const float4*)(E + (size_t)bS*NL);
        float4* dst = (float4*)Esh;
        #pragma unroll
        for (int j = 0; j < 6; ++j) dst[tid + (j << 8)] = src[tid + (j << 8)];
    }
    for (int i = tid; i < NL*NL; i += 256) {
        int c = i / NL, p = i % NL;
        Tt[i] = trans[p*NL + c];
    }
    if (tid < 64) {   // n = sum(true_label_mask[b]) = lengths[b]-2 (contiguous prefix)
        int a = tlm[bS+tid] + tlm[bS+tid+64] + tlm[bS+tid+128] + tlm[bS+tid+192];
        #pragma unroll
        for (int off = 32; off > 0; off >>= 1) a += __shfl_down(a, off, 64);
        if (tid == 0) nsh = a;
    }
    __syncthreads();
    const int n = nsh;   // n >= 1 always (lengths >= 3)

    // ---- forward pass: wave 0 only, lane = curr tag (replicated x2.67) ----
    if (tid < 64) {
        const int c = tid % 24;
        float Tc[24];                        // column c of transitions, in VGPRs
        #pragma unroll
        for (int p = 0; p < 24; ++p) Tc[p] = trans[p*NL + c];

        auto rl = [](float v, int p) {
            return __int_as_float(__builtin_amdgcn_readlane(__float_as_int(v), p));
        };

        float sv = st[c] + Esh[c];           // score0 = start + em[0]
        scl[c] = sv;
        float scr[24];
        #pragma unroll
        for (int p = 0; p < 24; ++p) scr[p] = rl(sv, p);

        float emn = Esh[NL + c];             // pipelined emission for t=1
        for (int t = 1; t < n; ++t) {
            float em = emn;
            int tn = (t+1 < n-1) ? t+1 : n-1;          // uniform, branchless
            emn = Esh[tn*NL + c];                       // issued before the chain below
            float cand[24];
            #pragma unroll
            for (int p = 0; p < 24; ++p) cand[p] = scr[p] + Tc[p];
            float m0 = fmaxf(fmaxf(cand[0],  cand[1]),  cand[2]);
            float m1 = fmaxf(fmaxf(cand[3],  cand[4]),  cand[5]);
            float m2 = fmaxf(fmaxf(cand[6],  cand[7]),  cand[8]);
            float m3 = fmaxf(fmaxf(cand[9],  cand[10]), cand[11]);
            float m4 = fmaxf(fmaxf(cand[12], cand[13]), cand[14]);
            float m5 = fmaxf(fmaxf(cand[15], cand[16]), cand[17]);
            float m6 = fmaxf(fmaxf(cand[18], cand[19]), cand[20]);
            float m7 = fmaxf(fmaxf(cand[21], cand[22]), cand[23]);
            float q0 = fmaxf(fmaxf(m0, m1), m2);
            float q1 = fmaxf(fmaxf(m3, m4), m5);
            float q2 = fmaxf(m6, m7);
            float best = fmaxf(fmaxf(q0, q1), q2);
            sv = best + em;
            scl[t*NL + c] = sv;              // off critical path (deferred argmax)
            #pragma unroll
            for (int p = 0; p < 24; ++p) scr[p] = rl(sv, p);
        }
        fin[c] = sv + en[c];
    }
    __syncthreads();

    if (tid == 0) {   // last_tag = argmax(final), first-max tie rule like jnp.argmax
        float bv = fin[0]; int bt = 0;
        #pragma unroll
        for (int cc = 1; cc < 24; ++cc) { if (fin[cc] > bv) { bv = fin[cc]; bt = cc; } }
        ltag = bt;
    }
    __syncthreads();

    // ---- backtrack: 10 windows x 24 hypotheses, recompute backpointers on the fly ----
    const int K = (n > 1) ? (n - 1 + 9) / 10 : 1;
    if (n > 1 && tid < 240) {
        const int w = tid / 24 + 1, h = tid % 24;
        int tlo = (w-1)*K; if (tlo > n-1) tlo = n-1;
        int thi = w*K;     if (thi > n-1) thi = n-1;
        int cur = h;                         // hypothesis: tag at time thi
        for (int t = thi; t > tlo; --t) {
            const float4* sp = (const float4*)(scl + (t-1)*NL);
            const float4* up = (const float4*)(Tt  + cur*NL);
            float cand[24];
            #pragma unroll
            for (int i = 0; i < 6; ++i) {
                float4 s = sp[i], u = up[i];
                cand[4*i+0] = s.x + u.x;     // bitwise-identical to forward cand
                cand[4*i+1] = s.y + u.y;
                cand[4*i+2] = s.z + u.z;
                cand[4*i+3] = s.w + u.w;
            }
            float best = cand[0]; int arg = 0;
            #pragma unroll
            for (int p = 1; p < 24; ++p) { if (cand[p] > best) { best = cand[p]; arg = p; } }
            tr_s[h][t-1] = (unsigned char)arg;
            cur = arg;
        }
    }
    __syncthreads();

    if (tid == 0) {   // stitch windows: chosen[w] = actual tag at window-top boundary
        int cur = ltag;
        for (int w = 10; w >= 1; --w) {
            chosen[w] = cur;
            int tlo = (w-1)*K; if (tlo > n-1) tlo = n-1;
            int thi = w*K;     if (thi > n-1) thi = n-1;
            if (thi > tlo) cur = tr_s[cur][tlo];
        }
    }
    __syncthreads();

    {   // emit path: t >= n-1 -> last_tag (identity backpointers on padding)
        const int t = tid;                   // 256 threads == NS
        int tag;
        if (t >= n-1) tag = ltag;
        else { int w = t / K + 1; tag = tr_s[chosen[w]][t]; }
        out[bS + t] = tag;
    }
}

extern "C" void kernel_launch(void* const* d_in, const int* in_sizes, int n_in,
                              void* d_out, int out_size, void* d_ws, size_t ws_size,
                              hipStream_t stream) {
    const float* tf    = (const float*)d_in[0];
    const int*   tlm   = (const int*)  d_in[2];   // true_label_mask
    const float* W     = (const float*)d_in[3];
    const float* bias  = (const float*)d_in[4];
    const float* trans = (const float*)d_in[5];
    const float* st    = (const float*)d_in[6];
    const float* en    = (const float*)d_in[7];
    float* E = (float*)d_ws;                      // [128,256,24] fp32 = 3.1 MB

    ner_emis<<<dim3(NB*4), dim3(256), 0, stream>>>(tf, tlm, W, bias, E);
    ner_viterbi<<<dim3(NB), dim3(256), 0, stream>>>(E, tlm, trans, st, en, (int*)d_out);
}

// Round 3
// 226.401 us; speedup vs baseline: 1.2823x; 1.0570x over previous
//
#include <hip/hip_runtime.h>
#include <hip/hip_bf16.h>
#include <math.h>

#define NB 128
#define NS 256
#define NH 768
#define NL 24

// ---------------- Kernel A: emissions = sigmoid(tf[b,t+1,:] @ W + b) for t < n_b ----
// grid 512 = 128 batches x 4 tiles of 64 tokens; block 256 = 4 waves; lane = token.
// K staged in 64-wide chunks (As stride 65: reads AND writes 2-way conflict-free).
// Wave w covers k-slice [w*16, w*16+16) of each chunk; W rows via wave-uniform s_load.
// LDS 29.4 KB -> 5 blocks/CU (vs 2 before): latency hiding was the round-2 bottleneck.
__global__ __launch_bounds__(256) void ner_emis(
    const float* __restrict__ tf, const int* __restrict__ tlm,
    const float* __restrict__ W, const float* __restrict__ bias,
    float* __restrict__ E)
{
    const int b    = blockIdx.x >> 2;
    const int tile = (blockIdx.x & 3) << 6;         // token base of this tile
    const int tid  = threadIdx.x;
    if (tlm[b*NS + tile] == 0) return;              // prefix mask: whole tile invalid

    __shared__ float As[64*65];                     // 64 tokens x 64 k, stride 65 (16.6 KB)
    __shared__ float P2[2*64*25];                   // pairwise partials, stride 25 (12.8 KB)

    const int lane = tid & 63;                      // token within tile
    const int w    = __builtin_amdgcn_readfirstlane(tid >> 6);  // wave id (SGPR)
    const int koff = w << 4;                        // this wave's 16-k slice base

    float acc[NL];
    #pragma unroll
    for (int l = 0; l < NL; ++l) acc[l] = 0.f;

    const float* tfb = tf + (size_t)(b*NS)*NH;

    for (int kc0 = 0; kc0 < NH; kc0 += 64) {
        // ---- stage A chunk [64 tok][64 k]: 1024 float4, 4 per thread, coalesced ----
        #pragma unroll
        for (int i = 0; i < 4; ++i) {
            int idx  = tid + (i << 8);
            int row  = idx >> 4;                    // token row 0..63
            int c4   = idx & 15;                    // float4 col 0..15
            int trow = tile + row + 1;              // feature row = token+1
            if (trow > 255) trow = 255;             // clamp (row is invalid anyway)
            float4 v = *(const float4*)(tfb + (size_t)trow*NH + kc0 + (c4 << 2));
            float* dst = As + row*65 + (c4 << 2);   // stride 65: 2-way banks = free
            dst[0] = v.x; dst[1] = v.y; dst[2] = v.z; dst[3] = v.w;
        }
        __syncthreads();

        // ---- compute: 16 k per wave, W row wave-uniform -> SGPR operand fmac ----
        #pragma unroll
        for (int k = 0; k < 16; ++k) {
            float a = As[lane*65 + koff + k];       // banks (lane+koff+k)%32: 2-way free
            const float* wr = W + (size_t)(kc0 + koff + k)*NL;
            #pragma unroll
            for (int l = 0; l < NL; ++l) acc[l] = fmaf(a, wr[l], acc[l]);
        }
        __syncthreads();
    }

    // ---- pairwise deterministic reduction: (w0+w1) + (w2+w3) ----
    if (w & 1) {                                    // waves 1,3 publish
        float* p = P2 + ((w >> 1)*64 + lane)*25;
        #pragma unroll
        for (int l = 0; l < NL; ++l) p[l] = acc[l];
    }
    __syncthreads();
    if (!(w & 1)) {                                 // waves 0,2 merge (fixed order lo+hi)
        const float* p = P2 + ((w >> 1)*64 + lane)*25;
        #pragma unroll
        for (int l = 0; l < NL; ++l) acc[l] += p[l];
    }
    __syncthreads();
    if (!(w & 1)) {                                 // publish merged halves
        float* p = P2 + ((w >> 1)*64 + lane)*25;
        #pragma unroll
        for (int l = 0; l < NL; ++l) p[l] = acc[l];
    }
    __syncthreads();

    const int* tm = tlm + b*NS + tile;
    float* Eb = E + (size_t)(b*NS + tile)*NL;
    #pragma unroll
    for (int j = 0; j < 6; ++j) {
        int idx = tid + (j << 8);                   // 0..1535 (64 tok x 24 lab)
        int tok = idx / NL, l = idx % NL;
        if (tm[tok]) {
            float s = P2[(0*64 + tok)*25 + l] + P2[(1*64 + tok)*25 + l];
            float x = s + bias[l];
            Eb[tok*NL + l] = 1.0f/(1.0f + expf(-x));
        }
    }
}

// ---------------- Kernel B: masked Viterbi decode, one block (256 thr) per batch ----
__global__ __launch_bounds__(256) void ner_viterbi(
    const float* __restrict__ E, const int* __restrict__ tlm,
    const float* __restrict__ trans, const float* __restrict__ st,
    const float* __restrict__ en, int* __restrict__ out)
{
    const int tid = threadIdx.x;
    const int b   = blockIdx.x;
    const int bS  = b*NS;

    __shared__ float Esh[NS*NL];            // preloaded emissions (24.5 KB)
    __shared__ float scl[NS*NL];            // per-step score vectors (24.5 KB)
    __shared__ float Tt[NL*NL];             // Tt[c*24+p] = T[p][c]
    __shared__ float fin[NL];
    __shared__ unsigned char tr_s[NL][NS];  // trace[hypothesis][t]
    __shared__ int chosen[12];
    __shared__ int nsh, ltag;

    {
        const float4* src = (const float4*)(E + (size_t)bS*NL);
        float4* dst = (float4*)Esh;
        #pragma unroll
        for (int j = 0; j < 6; ++j) dst[tid + (j << 8)] = src[tid + (j << 8)];
    }
    for (int i = tid; i < NL*NL; i += 256) {
        int c = i / NL, p = i % NL;
        Tt[i] = trans[p*NL + c];
    }
    if (tid < 64) {   // n = lengths[b]-2 (contiguous prefix mask)
        int a = tlm[bS+tid] + tlm[bS+tid+64] + tlm[bS+tid+128] + tlm[bS+tid+192];
        #pragma unroll
        for (int off = 32; off > 0; off >>= 1) a += __shfl_down(a, off, 64);
        if (tid == 0) nsh = a;
    }
    __syncthreads();
    const int n = nsh;   // n >= 1 always

    // ---- forward: wave 0, lane = curr tag; emissions prefetched 8 at a time ----
    if (tid < 64) {
        const int c = tid % 24;
        float Tc[24];
        #pragma unroll
        for (int p = 0; p < 24; ++p) Tc[p] = trans[p*NL + c];

        auto rl = [](float v, int p) {
            return __int_as_float(__builtin_amdgcn_readlane(__float_as_int(v), p));
        };

        float sv = st[c] + Esh[c];
        scl[c] = sv;
        float scr[24];
        #pragma unroll
        for (int p = 0; p < 24; ++p) scr[p] = rl(sv, p);

        auto step = [&](int t, float em) {
            float cand[24];
            #pragma unroll
            for (int p = 0; p < 24; ++p) cand[p] = scr[p] + Tc[p];
            float m0 = fmaxf(fmaxf(cand[0],  cand[1]),  cand[2]);
            float m1 = fmaxf(fmaxf(cand[3],  cand[4]),  cand[5]);
            float m2 = fmaxf(fmaxf(cand[6],  cand[7]),  cand[8]);
            float m3 = fmaxf(fmaxf(cand[9],  cand[10]), cand[11]);
            float m4 = fmaxf(fmaxf(cand[12], cand[13]), cand[14]);
            float m5 = fmaxf(fmaxf(cand[15], cand[16]), cand[17]);
            float m6 = fmaxf(fmaxf(cand[18], cand[19]), cand[20]);
            float m7 = fmaxf(fmaxf(cand[21], cand[22]), cand[23]);
            float q0 = fmaxf(fmaxf(m0, m1), m2);
            float q1 = fmaxf(fmaxf(m3, m4), m5);
            float q2 = fmaxf(m6, m7);
            float best = fmaxf(fmaxf(q0, q1), q2);
            sv = best + em;
            scl[t*NL + c] = sv;              // off critical path (deferred argmax)
            #pragma unroll
            for (int p = 0; p < 24; ++p) scr[p] = rl(sv, p);
        };

        int t = 1;
        for (; t + 8 <= n; t += 8) {
            float em[8];
            const float* eb = Esh + t*NL + c;
            #pragma unroll
            for (int j = 0; j < 8; ++j) em[j] = eb[j*NL];   // 8 indep ds_read, imm offs
            #pragma unroll
            for (int j = 0; j < 8; ++j) step(t + j, em[j]);
        }
        for (; t < n; ++t) step(t, Esh[t*NL + c]);
        fin[c] = sv + en[c];
    }
    __syncthreads();

    if (tid == 0) {   // argmax(final), first-max tie rule like jnp.argmax
        float bv = fin[0]; int bt = 0;
        #pragma unroll
        for (int cc = 1; cc < 24; ++cc) { if (fin[cc] > bv) { bv = fin[cc]; bt = cc; } }
        ltag = bt;
    }
    __syncthreads();

    // ---- backtrack: 10 windows x 24 hypotheses, recompute backpointers ----
    const int K = (n > 1) ? (n - 1 + 9) / 10 : 1;
    if (n > 1 && tid < 240) {
        const int w = tid / 24 + 1, h = tid % 24;
        int tlo = (w-1)*K; if (tlo > n-1) tlo = n-1;
        int thi = w*K;     if (thi > n-1) thi = n-1;
        int cur = h;
        for (int t = thi; t > tlo; --t) {
            const float4* sp = (const float4*)(scl + (t-1)*NL);
            const float4* up = (const float4*)(Tt  + cur*NL);
            float cand[24];
            #pragma unroll
            for (int i = 0; i < 6; ++i) {
                float4 s = sp[i], u = up[i];
                cand[4*i+0] = s.x + u.x;     // bitwise-identical to forward cand
                cand[4*i+1] = s.y + u.y;
                cand[4*i+2] = s.z + u.z;
                cand[4*i+3] = s.w + u.w;
            }
            float best = cand[0]; int arg = 0;
            #pragma unroll
            for (int p = 1; p < 24; ++p) { if (cand[p] > best) { best = cand[p]; arg = p; } }
            tr_s[h][t-1] = (unsigned char)arg;
            cur = arg;
        }
    }
    __syncthreads();

    if (tid == 0) {   // stitch windows
        int cur = ltag;
        for (int w = 10; w >= 1; --w) {
            chosen[w] = cur;
            int tlo = (w-1)*K; if (tlo > n-1) tlo = n-1;
            int thi = w*K;     if (thi > n-1) thi = n-1;
            if (thi > tlo) cur = tr_s[cur][tlo];
        }
    }
    __syncthreads();

    {   // emit path: t >= n-1 -> last_tag (identity backpointers on padding)
        const int t = tid;
        int tag;
        if (t >= n-1) tag = ltag;
        else { int w = t / K + 1; tag = tr_s[chosen[w]][t]; }
        out[bS + t] = tag;
    }
}

extern "C" void kernel_launch(void* const* d_in, const int* in_sizes, int n_in,
                              void* d_out, int out_size, void* d_ws, size_t ws_size,
                              hipStream_t stream) {
    const float* tf    = (const float*)d_in[0];
    const int*   tlm   = (const int*)  d_in[2];   // true_label_mask
    const float* W     = (const float*)d_in[3];
    const float* bias  = (const float*)d_in[4];
    const float* trans = (const float*)d_in[5];
    const float* st    = (const float*)d_in[6];
    const float* en    = (const float*)d_in[7];
    float* E = (float*)d_ws;                      // [128,256,24] fp32 = 3.1 MB

    ner_emis<<<dim3(NB*4), dim3(256), 0, stream>>>(tf, tlm, W, bias, E);
    ner_viterbi<<<dim3(NB), dim3(256), 0, stream>>>(E, tlm, trans, st, en, (int*)d_out);
}

// Round 4
// 207.456 us; speedup vs baseline: 1.3994x; 1.0913x over previous
//
#include <hip/hip_runtime.h>
#include <hip/hip_bf16.h>
#include <math.h>

#define NB 128
#define NS 256
#define NH 768
#define NL 24
#define ASTR 68   // A-tile LDS stride (words): 68%32=4 -> 2-way banks, 16B-aligned rows

// ---------------- Kernel A: emissions = sigmoid(tf[b,t+1,:] @ W + b) for t < n_b ----
// grid 1024 = 128 batches x 8 tiles of 32 tokens; block 256 thr = 4 waves.
// thread = (tok = tid&15, ksub = tid>>4); owns tokens {tok, tok+16}, k-slice of 4/chunk.
// W chunk (64k x 24) staged in LDS, read as broadcast ds_read_b128 (no s_load chain).
// Row-rotation j' = (s+ksub)&3 puts the 4 concurrent W rows on disjoint bank groups.
__global__ __launch_bounds__(256) void ner_emis(
    const float* __restrict__ tf, const int* __restrict__ tlm,
    const float* __restrict__ W, const float* __restrict__ bias,
    float* __restrict__ E)
{
    const int b    = blockIdx.x >> 3;
    const int tile = (blockIdx.x & 7) << 5;         // token base of this tile
    const int tid  = threadIdx.x;
    if (tlm[b*NS + tile] == 0) return;              // prefix mask: whole tile invalid

    __shared__ float lds[8*32*25];                  // 25.6 KB union
    float* As = lds;                                // [32][ASTR] = 2176 words (8.5 KB)
    float* Ws = lds + 32*ASTR;                      // [64][24]   = 1536 words (6 KB)
    float* Pr = lds;                                // [8][32][25] reduction (after K-loop)

    const int tok  = tid & 15;
    const int ksub = tid >> 4;                      // 0..15
    const int kk   = ksub << 2;                     // k base within 64-chunk
    const int rot  = ksub & 3;                      // bank-phase rotation

    float acc0[NL], acc1[NL];
    #pragma unroll
    for (int l = 0; l < NL; ++l) { acc0[l] = 0.f; acc1[l] = 0.f; }

    const float* tfb = tf + (size_t)(b*NS)*NH;

    for (int kc0 = 0; kc0 < NH; kc0 += 64) {
        // ---- stage A chunk [32 tok][64 k]: 512 float4, 2/thread, coalesced ----
        #pragma unroll
        for (int i = 0; i < 2; ++i) {
            int idx  = tid + (i << 8);
            int row  = idx >> 4;                    // token row 0..31
            int c4   = idx & 15;                    // float4 col 0..15
            int trow = tile + row + 1;              // feature row = token+1
            if (trow > 255) trow = 255;             // clamp (row invalid anyway)
            float4 v = *(const float4*)(tfb + (size_t)trow*NH + kc0 + (c4 << 2));
            float* dst = As + row*ASTR + (c4 << 2);
            dst[0] = v.x; dst[1] = v.y; dst[2] = v.z; dst[3] = v.w;
        }
        // ---- stage W chunk [64 k][24 l]: 384 contiguous float4 ----
        {
            const float4* wsrc = (const float4*)(W + (size_t)kc0*NL);
            float4* wdst = (float4*)Ws;
            for (int i = tid; i < 384; i += 256) wdst[i] = wsrc[i];
        }
        __syncthreads();

        const float* A0 = As + tok*ASTR + kk;
        const float* A1 = A0 + 16*ASTR;
        const float* Wr = Ws + kk*NL;
        #pragma unroll
        for (int s = 0; s < 4; ++s) {
            const int j = (s + rot) & 3;            // rotated row order (bank phase)
            float a0 = A0[j];
            float a1 = A1[j];
            const float4* w4 = (const float4*)(Wr + j*NL);
            float wv[NL];
            #pragma unroll
            for (int i = 0; i < 6; ++i) {           // 6 broadcast ds_read_b128
                float4 w = w4[i];
                wv[4*i+0] = w.x; wv[4*i+1] = w.y; wv[4*i+2] = w.z; wv[4*i+3] = w.w;
            }
            #pragma unroll
            for (int l = 0; l < NL; ++l) {
                acc0[l] = fmaf(a0, wv[l], acc0[l]);
                acc1[l] = fmaf(a1, wv[l], acc1[l]);
            }
        }
        __syncthreads();
    }

    // ---- fold 16 ksub partials -> 8 (ksub>=8 publish, ksub<8 add), then final ----
    if (ksub >= 8) {
        float* p = Pr + ((ksub-8)*32 + tok)*25;
        float* q = p + 16*25;
        #pragma unroll
        for (int l = 0; l < NL; ++l) { p[l] = acc0[l]; q[l] = acc1[l]; }
    }
    __syncthreads();
    if (ksub < 8) {
        const float* p = Pr + (ksub*32 + tok)*25;
        const float* q = p + 16*25;
        #pragma unroll
        for (int l = 0; l < NL; ++l) { acc0[l] += p[l]; acc1[l] += q[l]; }
    }
    __syncthreads();
    if (ksub < 8) {
        float* p = Pr + (ksub*32 + tok)*25;
        float* q = p + 16*25;
        #pragma unroll
        for (int l = 0; l < NL; ++l) { p[l] = acc0[l]; q[l] = acc1[l]; }
    }
    __syncthreads();

    const int* tm = tlm + b*NS + tile;
    float* Eb = E + (size_t)(b*NS + tile)*NL;
    #pragma unroll
    for (int i = 0; i < 3; ++i) {
        int o = tid + (i << 8);                     // 0..767 (32 tok x 24 lab)
        int t = o / NL, l = o % NL;
        if (tm[t]) {
            float s = 0.f;
            #pragma unroll
            for (int ks = 0; ks < 8; ++ks)          // fixed ascending order: deterministic
                s += Pr[(ks*32 + t)*25 + l];
            float x = s + bias[l];
            Eb[t*NL + l] = 1.0f/(1.0f + expf(-x));
        }
    }
}

// ---------------- Kernel B: masked Viterbi decode, one block (256 thr) per batch ----
__global__ __launch_bounds__(256) void ner_viterbi(
    const float* __restrict__ E, const int* __restrict__ tlm,
    const float* __restrict__ trans, const float* __restrict__ st,
    const float* __restrict__ en, int* __restrict__ out)
{
    const int tid = threadIdx.x;
    const int b   = blockIdx.x;
    const int bS  = b*NS;

    __shared__ float Esh[NS*NL];            // preloaded emissions (24.5 KB)
    __shared__ float scl[NS*NL];            // per-step score vectors (24.5 KB)
    __shared__ float Tt[NL*NL];             // Tt[c*24+p] = T[p][c]
    __shared__ float fin[NL];
    __shared__ unsigned char tr_s[NL][NS];  // trace[hypothesis][t]
    __shared__ int chosen[12];
    __shared__ int nsh, ltag;

    {
        const float4* src = (const float4*)(E + (size_t)bS*NL);
        float4* dst = (float4*)Esh;
        #pragma unroll
        for (int j = 0; j < 6; ++j) dst[tid + (j << 8)] = src[tid + (j << 8)];
    }
    for (int i = tid; i < NL*NL; i += 256) {
        int c = i / NL, p = i % NL;
        Tt[i] = trans[p*NL + c];
    }
    if (tid < 64) {   // n = lengths[b]-2 (contiguous prefix mask)
        int a = tlm[bS+tid] + tlm[bS+tid+64] + tlm[bS+tid+128] + tlm[bS+tid+192];
        #pragma unroll
        for (int off = 32; off > 0; off >>= 1) a += __shfl_down(a, off, 64);
        if (tid == 0) nsh = a;
    }
    __syncthreads();
    const int n = nsh;   // n >= 1 always

    // ---- forward: wave 0, lane = curr tag; emissions prefetched 8 at a time ----
    if (tid < 64) {
        const int c = tid % 24;
        float Tc[24];
        #pragma unroll
        for (int p = 0; p < 24; ++p) Tc[p] = trans[p*NL + c];

        auto rl = [](float v, int p) {
            return __int_as_float(__builtin_amdgcn_readlane(__float_as_int(v), p));
        };

        float sv = st[c] + Esh[c];
        scl[c] = sv;
        float scr[24];
        #pragma unroll
        for (int p = 0; p < 24; ++p) scr[p] = rl(sv, p);

        auto step = [&](int t, float em) {
            float cand[24];
            #pragma unroll
            for (int p = 0; p < 24; ++p) cand[p] = scr[p] + Tc[p];
            float m0 = fmaxf(fmaxf(cand[0],  cand[1]),  cand[2]);
            float m1 = fmaxf(fmaxf(cand[3],  cand[4]),  cand[5]);
            float m2 = fmaxf(fmaxf(cand[6],  cand[7]),  cand[8]);
            float m3 = fmaxf(fmaxf(cand[9],  cand[10]), cand[11]);
            float m4 = fmaxf(fmaxf(cand[12], cand[13]), cand[14]);
            float m5 = fmaxf(fmaxf(cand[15], cand[16]), cand[17]);
            float m6 = fmaxf(fmaxf(cand[18], cand[19]), cand[20]);
            float m7 = fmaxf(fmaxf(cand[21], cand[22]), cand[23]);
            float q0 = fmaxf(fmaxf(m0, m1), m2);
            float q1 = fmaxf(fmaxf(m3, m4), m5);
            float q2 = fmaxf(m6, m7);
            float best = fmaxf(fmaxf(q0, q1), q2);
            sv = best + em;
            scl[t*NL + c] = sv;              // off critical path (deferred argmax)
            #pragma unroll
            for (int p = 0; p < 24; ++p) scr[p] = rl(sv, p);
        };

        int t = 1;
        for (; t + 8 <= n; t += 8) {
            float em[8];
            const float* eb = Esh + t*NL + c;
            #pragma unroll
            for (int j = 0; j < 8; ++j) em[j] = eb[j*NL];   // 8 indep ds_read, imm offs
            #pragma unroll
            for (int j = 0; j < 8; ++j) step(t + j, em[j]);
        }
        for (; t < n; ++t) step(t, Esh[t*NL + c]);
        fin[c] = sv + en[c];
    }
    __syncthreads();

    if (tid == 0) {   // argmax(final), first-max tie rule like jnp.argmax
        float bv = fin[0]; int bt = 0;
        #pragma unroll
        for (int cc = 1; cc < 24; ++cc) { if (fin[cc] > bv) { bv = fin[cc]; bt = cc; } }
        ltag = bt;
    }
    __syncthreads();

    // ---- backtrack: 10 windows x 24 hypotheses, recompute backpointers ----
    const int K = (n > 1) ? (n - 1 + 9) / 10 : 1;
    if (n > 1 && tid < 240) {
        const int w = tid / 24 + 1, h = tid % 24;
        int tlo = (w-1)*K; if (tlo > n-1) tlo = n-1;
        int thi = w*K;     if (thi > n-1) thi = n-1;
        int cur = h;
        for (int t = thi; t > tlo; --t) {
            const float4* sp = (const float4*)(scl + (t-1)*NL);
            const float4* up = (const float4*)(Tt  + cur*NL);
            float cand[24];
            #pragma unroll
            for (int i = 0; i < 6; ++i) {
                float4 s = sp[i], u = up[i];
                cand[4*i+0] = s.x + u.x;     // bitwise-identical to forward cand
                cand[4*i+1] = s.y + u.y;
                cand[4*i+2] = s.z + u.z;
                cand[4*i+3] = s.w + u.w;
            }
            float best = cand[0]; int arg = 0;
            #pragma unroll
            for (int p = 1; p < 24; ++p) { if (cand[p] > best) { best = cand[p]; arg = p; } }
            tr_s[h][t-1] = (unsigned char)arg;
            cur = arg;
        }
    }
    __syncthreads();

    if (tid == 0) {   // stitch windows
        int cur = ltag;
        for (int w = 10; w >= 1; --w) {
            chosen[w] = cur;
            int tlo = (w-1)*K; if (tlo > n-1) tlo = n-1;
            int thi = w*K;     if (thi > n-1) thi = n-1;
            if (thi > tlo) cur = tr_s[cur][tlo];
        }
    }
    __syncthreads();

    {   // emit path: t >= n-1 -> last_tag (identity backpointers on padding)
        const int t = tid;
        int tag;
        if (t >= n-1) tag = ltag;
        else { int w = t / K + 1; tag = tr_s[chosen[w]][t]; }
        out[bS + t] = tag;
    }
}

extern "C" void kernel_launch(void* const* d_in, const int* in_sizes, int n_in,
                              void* d_out, int out_size, void* d_ws, size_t ws_size,
                              hipStream_t stream) {
    const float* tf    = (const float*)d_in[0];
    const int*   tlm   = (const int*)  d_in[2];   // true_label_mask
    const float* W     = (const float*)d_in[3];
    const float* bias  = (const float*)d_in[4];
    const float* trans = (const float*)d_in[5];
    const float* st    = (const float*)d_in[6];
    const float* en    = (const float*)d_in[7];
    float* E = (float*)d_ws;                      // [128,256,24] fp32 = 3.1 MB

    ner_emis<<<dim3(NB*8), dim3(256), 0, stream>>>(tf, tlm, W, bias, E);
    ner_viterbi<<<dim3(NB), dim3(256), 0, stream>>>(E, tlm, trans, st, en, (int*)d_out);
}